// Round 5
// baseline (284.118 us; speedup 1.0000x reference)
//
#include <hip/hip_runtime.h>

// SpatialTransformer: 3D trilinear warp with dense displacement field.
// vol: [B,D,H,W,C] f32, trf: [B,D,H,W,3] f32 -> out: [B,D,H,W,C] f32
// B=2, D=H=W=160, C=2 (fixed by setup_inputs).
//
// R10: batch-split main dispatch for L3 residency.
// Model (fits R4/R8/R9): time ~ unique-line-touches x avg-latency / MSHRs.
// R9 cut lines 2.57->1.57/voxel but overflowed L3 (pk 131 + trf 98 + out 64
// = 293 MB > 256): FETCH rose 87.5->122 MB, avg latency ~200->~305 cyc,
// canceling the gain (107->101 only). Fix: the two batches share NOTHING
// (cells are per-batch), so run the main kernel twice, once per batch:
// per-dispatch set = pk/2 65.5 + trf/2 49 + out/2 32 = 147 MB << 256 MB.
// Keeps R9's 1.25-line cell gather at R8's L3-hit latency.
// Predict: combined main 65-75us (from 101), FETCH/half ~50-55 MB,
// total ~250us (dur_us carries ~142us fixed harness overhead).
//
// Per-dispatch XCD regions: 8 h-slices of HQ2=20 rows (was 2b x 4 quarters).
// Numerics identical to R9 (fp16 cell values, f32 weights from untouched
// trf; absmax 0.25 accepted - boundary extrapolation amplifies fp16 eps).
// Fallback tiers: ws>=131MB -> R10; ws>=65.5MB -> R8 path; else R5 f32.

#define BLK 256
constexpr int Bn = 2, Dn = 160, Hn = 160, Wn = 160;
constexpr int HQ = 40;                    // h-quarter rows (R8/R5 fallback paths)
constexpr int RSTRIP = HQ * Wn;           // 6400 voxels per (d, quarter) plane
constexpr int HQ2 = 20;                   // h-slice rows per XCD region (R10 split)
constexpr int RSTRIP2 = HQ2 * Wn;         // 3200 voxels per (d, slice) plane
constexpr int V = 4;                      // voxels per thread

typedef float    f32x2  __attribute__((ext_vector_type(2)));
typedef float    f32x4  __attribute__((ext_vector_type(4), aligned(8)));   // vol reads: 8B-aligned
typedef _Float16 h16x8  __attribute__((ext_vector_type(8), aligned(8)));   // R8 chunk at byte 8p
typedef _Float16 h16x16 __attribute__((ext_vector_type(16), aligned(16))); // cell pair at byte 16p

// ================= repack: vol f32 -> P16[p][8] = 8 cell corners ===========
// P16[p] = {d0h0c0,d0h0c1,d0h1c0,d0h1c1,d1h0c0,d1h0c1,d1h1c0,d1h1c1},
// d1/h1 clamp-baked. Each thread packs 2 consecutive-w voxels.
__global__ __launch_bounds__(BLK) void repack_dh(
    const float* __restrict__ vol, _Float16* __restrict__ pk)
{
    const int t  = blockIdx.x * BLK + threadIdx.x;   // 0 .. nvox/2-1
    const int v0 = t * 2;                            // even voxel id
    const int w  = v0 % Wn;                          // even (Wn%2==0)
    const int r  = v0 / Wn;                          // row id = (b*Dn+d)*Hn+h
    const int h  = r % Hn;
    const int d  = (r / Hn) % Dn;
    const int dh = (h < Hn - 1) ? 1 : 0;             // h-step (clamped)
    const int dd = (d < Dn - 1) ? Hn : 0;            // d-step in rows (clamped)

    const int r00 = r;                               // (d ,h )
    const int r01 = r + dh;                          // (d ,h1)
    const int r10 = r + dd;                          // (d1,h )
    const int r11 = r + dd + dh;                     // (d1,h1)

    const f32x4 A = *(const f32x4*)(vol + ((long long)(r00 * Wn + w) << 1));
    const f32x4 B = *(const f32x4*)(vol + ((long long)(r01 * Wn + w) << 1));
    const f32x4 C = *(const f32x4*)(vol + ((long long)(r10 * Wn + w) << 1));
    const f32x4 D = *(const f32x4*)(vol + ((long long)(r11 * Wn + w) << 1));

    h16x16 o;
    // voxel v0 (w):    x=c0, y=c1
    o[0]  = (_Float16)A.x; o[1]  = (_Float16)A.y;    // d0h0
    o[2]  = (_Float16)B.x; o[3]  = (_Float16)B.y;    // d0h1
    o[4]  = (_Float16)C.x; o[5]  = (_Float16)C.y;    // d1h0
    o[6]  = (_Float16)D.x; o[7]  = (_Float16)D.y;    // d1h1
    // voxel v0+1 (w+1): z=c0, w=c1
    o[8]  = (_Float16)A.z; o[9]  = (_Float16)A.w;
    o[10] = (_Float16)B.z; o[11] = (_Float16)B.w;
    o[12] = (_Float16)C.z; o[13] = (_Float16)C.w;
    o[14] = (_Float16)D.z; o[15] = (_Float16)D.w;
    *(h16x16*)(pk + ((long long)v0 << 3)) = o;       // 32B at byte 16*v0
}

// ================= R10 main: one batch per dispatch ========================
__global__ __launch_bounds__(BLK, 4) void st_warp_kernel_pk16(
    const _Float16* __restrict__ pk,
    const float* __restrict__ trf,
    float* __restrict__ out,
    const int b)
{
    const int tid = threadIdx.x;
    const int sl  = blockIdx.x & 7;          // h-slice region (XCD heuristic)
    const int j   = blockIdx.x >> 3;         // 0..499 within region
    const int h0  = sl * HQ2;                // h-slice origin

    // ---- phase 0: voxel ids + all trf loads (12 dwords in flight) ----
    int   gvox[V];
    float sd[V], sh[V], sw[V];
    #pragma unroll
    for (int k = 0; k < V; ++k) {
        const int v   = j * (BLK * V) + k * BLK + tid;   // region-linear voxel
        const int d   = v / RSTRIP2;
        const int rem = v - d * RSTRIP2;
        const int hh  = rem / Wn;
        const int w   = rem - hh * Wn;
        gvox[k] = ((b * Dn + d) * Hn + (h0 + hh)) * Wn + w;
    }
    #pragma unroll
    for (int k = 0; k < V; ++k) {
        const float* tp = trf + (long long)gvox[k] * 3;
        sd[k] = __builtin_nontemporal_load(tp + 0);
        sh[k] = __builtin_nontemporal_load(tp + 1);
        sw[k] = __builtin_nontemporal_load(tp + 2);
    }

    // ---- phase 1: weights + issue all V 32B cell gathers ----
    h16x16 val[V];
    float wA[V], wB[V], wC[V], wD[V], w0[V], w1[V];
    #pragma unroll
    for (int k = 0; k < V; ++k) {
        const int v   = j * (BLK * V) + k * BLK + tid;
        const int d   = v / RSTRIP2;
        const int rem = v - d * RSTRIP2;
        const int hh  = rem / Wn;
        const int w   = rem - hh * Wn;
        const int h   = h0 + hh;

        float loc, c0f, c1f;

        loc = (float)d + sd[k];
        c0f = fminf(fmaxf(floorf(loc), 0.0f), (float)(Dn - 1));
        c1f = fminf(c0f + 1.0f, (float)(Dn - 1));
        const float wd0 = c1f - loc, wd1 = 1.0f - wd0;
        const int id0 = (int)c0f;                 // id1 baked into packed data

        loc = (float)h + sh[k];
        c0f = fminf(fmaxf(floorf(loc), 0.0f), (float)(Hn - 1));
        c1f = fminf(c0f + 1.0f, (float)(Hn - 1));
        const float wh0 = c1f - loc, wh1 = 1.0f - wh0;
        const int ih0 = (int)c0f;                 // ih1 baked into packed data

        loc = (float)w + sw[k];
        c0f = fminf(fmaxf(floorf(loc), 0.0f), (float)(Wn - 1));
        c1f = fminf(c0f + 1.0f, (float)(Wn - 1));
        const float ww0 = c1f - loc, ww1 = 1.0f - ww0;
        const int iw0 = (int)c0f;

        const bool lo = (iw0 < Wn - 1);
        const int  m  = lo ? iw0 : (Wn - 2);
        // boundary: corner0 weight -> 0, corner1 weight -> 1 (exact: ww0+ww1==1)
        w0[k] = lo ? ww0 : 0.0f;
        w1[k] = lo ? ww1 : 1.0f;
        wA[k] = wd0 * wh0; wB[k] = wd0 * wh1;
        wC[k] = wd1 * wh0; wD[k] = wd1 * wh1;

        const long long p0 = ((b * Dn + id0) * Hn + ih0) * Wn + m;  // w-pair base
        val[k] = *(const h16x16*)(pk + (p0 << 3));   // 32B: cells p0, p0+1
    }

    // ---- phase 2: convert + combine + store ----
    #pragma unroll
    for (int k = 0; k < V; ++k) {
        const h16x16 v = val[k];
        // layout: [i] w-corner0, [8+i] w-corner1; i = d*4 + h*2 + c
        const float acc0 =
              wA[k] * (w0[k] * (float)v[0] + w1[k] * (float)v[8])
            + wB[k] * (w0[k] * (float)v[2] + w1[k] * (float)v[10])
            + wC[k] * (w0[k] * (float)v[4] + w1[k] * (float)v[12])
            + wD[k] * (w0[k] * (float)v[6] + w1[k] * (float)v[14]);
        const float acc1 =
              wA[k] * (w0[k] * (float)v[1] + w1[k] * (float)v[9])
            + wB[k] * (w0[k] * (float)v[3] + w1[k] * (float)v[11])
            + wC[k] * (w0[k] * (float)v[5] + w1[k] * (float)v[13])
            + wD[k] * (w0[k] * (float)v[7] + w1[k] * (float)v[15]);
        f32x2 res; res.x = acc0; res.y = acc1;
        __builtin_nontemporal_store(res, &((f32x2*)out)[gvox[k]]);
    }
}

// ================= R8 tier: h-pair pack (known-good middle fallback) =======
__global__ __launch_bounds__(BLK) void repack_h_pairs(
    const float* __restrict__ vol, _Float16* __restrict__ pk)
{
    const int t  = blockIdx.x * BLK + threadIdx.x;   // 0 .. 4,095,999
    const int v0 = t * 2;                            // even voxel id
    const int w  = v0 % Wn;                          // even (Wn%2==0)
    const int r  = v0 / Wn;                          // row id = (b*Dn+d)*Hn+h
    const int h  = r % Hn;
    const int hc = (h < Hn - 1) ? (h + 1) : h;       // clamped h+1
    const int r1 = r - h + hc;                       // row id at hc

    const f32x4 a = *(const f32x4*)(vol + ((long long)v0 << 1));
    const f32x4 b = *(const f32x4*)(vol + ((long long)(r1 * Wn + w) << 1));

    h16x8 o;
    o[0] = (_Float16)a.x; o[1] = (_Float16)a.y;
    o[2] = (_Float16)b.x; o[3] = (_Float16)b.y;
    o[4] = (_Float16)a.z; o[5] = (_Float16)a.w;
    o[6] = (_Float16)b.z; o[7] = (_Float16)b.w;
    *(h16x8*)(pk + ((long long)v0 << 2)) = o;
}

__global__ __launch_bounds__(BLK, 4) void st_warp_kernel_pk(
    const _Float16* __restrict__ pk,
    const float* __restrict__ trf,
    float* __restrict__ out)
{
    const int tid = threadIdx.x;
    const int xcd = blockIdx.x & 7;
    const int j   = blockIdx.x >> 3;
    const int b   = xcd >> 2;
    const int h0  = (xcd & 3) * HQ;

    int   gvox[V];
    float sd[V], sh[V], sw[V];
    #pragma unroll
    for (int k = 0; k < V; ++k) {
        const int v   = j * (BLK * V) + k * BLK + tid;
        const int d   = v / RSTRIP;
        const int rem = v - d * RSTRIP;
        const int hh  = rem / Wn;
        const int w   = rem - hh * Wn;
        gvox[k] = ((b * Dn + d) * Hn + (h0 + hh)) * Wn + w;
    }
    #pragma unroll
    for (int k = 0; k < V; ++k) {
        const float* tp = trf + (long long)gvox[k] * 3;
        sd[k] = __builtin_nontemporal_load(tp + 0);
        sh[k] = __builtin_nontemporal_load(tp + 1);
        sw[k] = __builtin_nontemporal_load(tp + 2);
    }

    h16x8 val[2 * V];
    float wA[V], wB[V], wC[V], wD[V], w0[V], w1[V];
    #pragma unroll
    for (int k = 0; k < V; ++k) {
        const int v   = j * (BLK * V) + k * BLK + tid;
        const int d   = v / RSTRIP;
        const int rem = v - d * RSTRIP;
        const int hh  = rem / Wn;
        const int w   = rem - hh * Wn;
        const int h   = h0 + hh;

        float loc, c0f, c1f;

        loc = (float)d + sd[k];
        c0f = fminf(fmaxf(floorf(loc), 0.0f), (float)(Dn - 1));
        c1f = fminf(c0f + 1.0f, (float)(Dn - 1));
        const float wd0 = c1f - loc, wd1 = 1.0f - wd0;
        const int id0 = (int)c0f, id1 = (int)c1f;

        loc = (float)h + sh[k];
        c0f = fminf(fmaxf(floorf(loc), 0.0f), (float)(Hn - 1));
        c1f = fminf(c0f + 1.0f, (float)(Hn - 1));
        const float wh0 = c1f - loc, wh1 = 1.0f - wh0;
        const int ih0 = (int)c0f;

        loc = (float)w + sw[k];
        c0f = fminf(fmaxf(floorf(loc), 0.0f), (float)(Wn - 1));
        c1f = fminf(c0f + 1.0f, (float)(Wn - 1));
        const float ww0 = c1f - loc, ww1 = 1.0f - ww0;
        const int iw0 = (int)c0f;

        const bool lo = (iw0 < Wn - 1);
        const int  m  = lo ? iw0 : (Wn - 2);
        w0[k] = lo ? ww0 : 0.0f;
        w1[k] = lo ? ww1 : 1.0f;
        wA[k] = wd0 * wh0; wB[k] = wd0 * wh1;
        wC[k] = wd1 * wh0; wD[k] = wd1 * wh1;

        const int bo = b * Dn;
        const int p0 = ((bo + id0) * Hn + ih0) * Wn + m;
        const int p1 = ((bo + id1) * Hn + ih0) * Wn + m;

        val[2 * k + 0] = *(const h16x8*)(pk + ((long long)p0 << 2));
        val[2 * k + 1] = *(const h16x8*)(pk + ((long long)p1 << 2));
    }

    #pragma unroll
    for (int k = 0; k < V; ++k) {
        const h16x8 a = val[2 * k + 0];
        const h16x8 c = val[2 * k + 1];
        const float acc0 =
              wA[k] * (w0[k] * (float)a[0] + w1[k] * (float)a[4])
            + wB[k] * (w0[k] * (float)a[2] + w1[k] * (float)a[6])
            + wC[k] * (w0[k] * (float)c[0] + w1[k] * (float)c[4])
            + wD[k] * (w0[k] * (float)c[2] + w1[k] * (float)c[6]);
        const float acc1 =
              wA[k] * (w0[k] * (float)a[1] + w1[k] * (float)a[5])
            + wB[k] * (w0[k] * (float)a[3] + w1[k] * (float)a[7])
            + wC[k] * (w0[k] * (float)c[1] + w1[k] * (float)c[5])
            + wD[k] * (w0[k] * (float)c[3] + w1[k] * (float)c[7]);
        f32x2 res; res.x = acc0; res.y = acc1;
        __builtin_nontemporal_store(res, &((f32x2*)out)[gvox[k]]);
    }
}

// ================= R5 tier: f32 direct (last-resort fallback) ==============
__global__ __launch_bounds__(BLK, 4) void st_warp_kernel_f32(
    const float* __restrict__ vol,
    const float* __restrict__ trf,
    float* __restrict__ out)
{
    const int tid = threadIdx.x;
    const int xcd = blockIdx.x & 7;
    const int j   = blockIdx.x >> 3;
    const int b   = xcd >> 2;
    const int h0  = (xcd & 3) * HQ;

    int   gvox[V];
    float sd[V], sh[V], sw[V];
    #pragma unroll
    for (int k = 0; k < V; ++k) {
        const int v   = j * (BLK * V) + k * BLK + tid;
        const int d   = v / RSTRIP;
        const int rem = v - d * RSTRIP;
        const int hh  = rem / Wn;
        const int w   = rem - hh * Wn;
        gvox[k] = ((b * Dn + d) * Hn + (h0 + hh)) * Wn + w;
    }
    #pragma unroll
    for (int k = 0; k < V; ++k) {
        const float* tp = trf + (long long)gvox[k] * 3;
        sd[k] = __builtin_nontemporal_load(tp + 0);
        sh[k] = __builtin_nontemporal_load(tp + 1);
        sw[k] = __builtin_nontemporal_load(tp + 2);
    }

    f32x4 val[4 * V];
    float wA[V], wB[V], wC[V], wD[V], w0[V], w1[V];
    #pragma unroll
    for (int k = 0; k < V; ++k) {
        const int v   = j * (BLK * V) + k * BLK + tid;
        const int d   = v / RSTRIP;
        const int rem = v - d * RSTRIP;
        const int hh  = rem / Wn;
        const int w   = rem - hh * Wn;
        const int h   = h0 + hh;

        float loc, c0f, c1f;

        loc = (float)d + sd[k];
        c0f = fminf(fmaxf(floorf(loc), 0.0f), (float)(Dn - 1));
        c1f = fminf(c0f + 1.0f, (float)(Dn - 1));
        const float wd0 = c1f - loc, wd1 = 1.0f - wd0;
        const int id0 = (int)c0f, id1 = (int)c1f;

        loc = (float)h + sh[k];
        c0f = fminf(fmaxf(floorf(loc), 0.0f), (float)(Hn - 1));
        c1f = fminf(c0f + 1.0f, (float)(Hn - 1));
        const float wh0 = c1f - loc, wh1 = 1.0f - wh0;
        const int ih0 = (int)c0f, ih1 = (int)c1f;

        loc = (float)w + sw[k];
        c0f = fminf(fmaxf(floorf(loc), 0.0f), (float)(Wn - 1));
        c1f = fminf(c0f + 1.0f, (float)(Wn - 1));
        const float ww0 = c1f - loc, ww1 = 1.0f - ww0;
        const int iw0 = (int)c0f;

        const bool lo = (iw0 < Wn - 1);
        const int  m  = lo ? iw0 : (Wn - 2);
        w0[k] = lo ? ww0 : 0.0f;
        w1[k] = lo ? ww1 : 1.0f;
        wA[k] = wd0 * wh0; wB[k] = wd0 * wh1;
        wC[k] = wd1 * wh0; wD[k] = wd1 * wh1;

        const int bo  = b * Dn;
        const int r00 = ((bo + id0) * Hn + ih0) * Wn;
        const int r01 = ((bo + id0) * Hn + ih1) * Wn;
        const int r10 = ((bo + id1) * Hn + ih0) * Wn;
        const int r11 = ((bo + id1) * Hn + ih1) * Wn;

        val[4 * k + 0] = *(const f32x4*)(vol + (((long long)(r00 + m)) << 1));
        val[4 * k + 1] = *(const f32x4*)(vol + (((long long)(r01 + m)) << 1));
        val[4 * k + 2] = *(const f32x4*)(vol + (((long long)(r10 + m)) << 1));
        val[4 * k + 3] = *(const f32x4*)(vol + (((long long)(r11 + m)) << 1));
    }

    #pragma unroll
    for (int k = 0; k < V; ++k) {
        const f32x4 vA = val[4 * k + 0], vB = val[4 * k + 1];
        const f32x4 vC = val[4 * k + 2], vD = val[4 * k + 3];
        const float acc0 = wA[k] * (w0[k] * vA.x + w1[k] * vA.z)
                         + wB[k] * (w0[k] * vB.x + w1[k] * vB.z)
                         + wC[k] * (w0[k] * vC.x + w1[k] * vC.z)
                         + wD[k] * (w0[k] * vD.x + w1[k] * vD.z);
        const float acc1 = wA[k] * (w0[k] * vA.y + w1[k] * vA.w)
                         + wB[k] * (w0[k] * vB.y + w1[k] * vB.w)
                         + wC[k] * (w0[k] * vC.y + w1[k] * vC.w)
                         + wD[k] * (w0[k] * vD.y + w1[k] * vD.w);
        f32x2 res; res.x = acc0; res.y = acc1;
        __builtin_nontemporal_store(res, &((f32x2*)out)[gvox[k]]);
    }
}

extern "C" void kernel_launch(void* const* d_in, const int* in_sizes, int n_in,
                              void* d_out, int out_size, void* d_ws, size_t ws_size,
                              hipStream_t stream) {
    const float* vol = (const float*)d_in[0];
    const float* trf = (const float*)d_in[1];
    float* out = (float*)d_out;

    const int nvox = Bn * Dn * Hn * Wn;               // 8,192,000
    const size_t pk16_bytes = (size_t)nvox * 8 * sizeof(_Float16);  // 131,072,000
    const size_t pk8_bytes  = (size_t)nvox * 4 * sizeof(_Float16);  //  65,536,000
    const int rgrid = (nvox / 2) / BLK;               // 16000 blocks

    if (d_ws != nullptr && ws_size >= pk16_bytes) {
        _Float16* pk = (_Float16*)d_ws;
        const int hgrid = (nvox / 2) / (BLK * V);     // 4000 blocks per batch, %8==0
        repack_dh<<<rgrid, BLK, 0, stream>>>(vol, pk);
        st_warp_kernel_pk16<<<hgrid, BLK, 0, stream>>>(pk, trf, out, 0);
        st_warp_kernel_pk16<<<hgrid, BLK, 0, stream>>>(pk, trf, out, 1);
    } else if (d_ws != nullptr && ws_size >= pk8_bytes) {
        _Float16* pk = (_Float16*)d_ws;
        const int grid = nvox / (BLK * V);            // 8000 blocks
        repack_h_pairs<<<rgrid, BLK, 0, stream>>>(vol, pk);
        st_warp_kernel_pk<<<grid, BLK, 0, stream>>>(pk, trf, out);
    } else {
        const int grid = nvox / (BLK * V);
        st_warp_kernel_f32<<<grid, BLK, 0, stream>>>(vol, trf, out);
    }
}

// Round 6
// 276.717 us; speedup vs baseline: 1.0267x; 1.0267x over previous
//
#include <hip/hip_runtime.h>

// SpatialTransformer: 3D trilinear warp with dense displacement field.
// vol: [B,D,H,W,C] f32, trf: [B,D,H,W,3] f32 -> out: [B,D,H,W,C] f32
// B=2, D=H=W=160, C=2 (fixed by setup_inputs).
//
// R11: force MLP with sched_barrier. Post-mortem R10: batch-split neutral
// (main still ~100us combined). Smoking gun: VGPR_Count=32 in ALL rounds --
// the compiler re-fuses the phased source into per-voxel
// {weights, 2 loads, wait, accumulate, store}: effective MLP ~= 2 scattered
// loads/wave. With VALU 16%, HBM ~20%, occ 77%, 0 conflicts, nothing is
// saturated -> LATENCY-bound at MLP~2. This also explains R5's neutral "MLP
// attack" (compiler undid it; VGPR stayed 32) and R9/R10 flatness (fewer
// unique lines don't matter when latency x (misses/in-flight) dominates).
// Fix: __builtin_amdgcn_sched_barrier(0) after the trf-load block and after
// the cell-load block -- nothing may cross, so all 12 trf dwords then all
// 8 cell dwordx4 per thread genuinely stay in flight (MLP 2 -> 8).
// Compile-time fence only; zero numerics impact.
// Predict: VGPR 32 -> ~90-110 (proof the barrier took), occupancy ~55-65%,
// combined main 100 -> 45-65us, total 284 -> ~230-250us, absmax 0.25.
//
// Retained: fp16 full-cell pack P16[p][8] (d1/h1 clamp-baked, 32B/cell,
// 131MB ws), batch-split main (2 dispatches, per-dispatch set 147MB < L3),
// 8 h-slice XCD regions, V=4, nontemporal trf/out, w-boundary folded into
// weights (exact). Fallback tiers: ws>=131MB -> R11; >=65.5MB -> R8; else f32.

#define BLK 256
constexpr int Bn = 2, Dn = 160, Hn = 160, Wn = 160;
constexpr int HQ = 40;                    // h-quarter rows (R8/R5 fallback paths)
constexpr int RSTRIP = HQ * Wn;           // 6400 voxels per (d, quarter) plane
constexpr int HQ2 = 20;                   // h-slice rows per XCD region (split)
constexpr int RSTRIP2 = HQ2 * Wn;         // 3200 voxels per (d, slice) plane
constexpr int V = 4;                      // voxels per thread

typedef float    f32x2  __attribute__((ext_vector_type(2)));
typedef float    f32x4  __attribute__((ext_vector_type(4), aligned(8)));   // vol reads: 8B-aligned
typedef _Float16 h16x8  __attribute__((ext_vector_type(8), aligned(8)));   // R8 chunk at byte 8p
typedef _Float16 h16x16 __attribute__((ext_vector_type(16), aligned(16))); // cell pair at byte 16p

// ================= repack: vol f32 -> P16[p][8] = 8 cell corners ===========
// P16[p] = {d0h0c0,d0h0c1,d0h1c0,d0h1c1,d1h0c0,d1h0c1,d1h1c0,d1h1c1},
// d1/h1 clamp-baked. Each thread packs 2 consecutive-w voxels.
__global__ __launch_bounds__(BLK) void repack_dh(
    const float* __restrict__ vol, _Float16* __restrict__ pk)
{
    const int t  = blockIdx.x * BLK + threadIdx.x;   // 0 .. nvox/2-1
    const int v0 = t * 2;                            // even voxel id
    const int w  = v0 % Wn;                          // even (Wn%2==0)
    const int r  = v0 / Wn;                          // row id = (b*Dn+d)*Hn+h
    const int h  = r % Hn;
    const int d  = (r / Hn) % Dn;
    const int dh = (h < Hn - 1) ? 1 : 0;             // h-step (clamped)
    const int dd = (d < Dn - 1) ? Hn : 0;            // d-step in rows (clamped)

    const int r00 = r;                               // (d ,h )
    const int r01 = r + dh;                          // (d ,h1)
    const int r10 = r + dd;                          // (d1,h )
    const int r11 = r + dd + dh;                     // (d1,h1)

    const f32x4 A = *(const f32x4*)(vol + ((long long)(r00 * Wn + w) << 1));
    const f32x4 B = *(const f32x4*)(vol + ((long long)(r01 * Wn + w) << 1));
    const f32x4 C = *(const f32x4*)(vol + ((long long)(r10 * Wn + w) << 1));
    const f32x4 D = *(const f32x4*)(vol + ((long long)(r11 * Wn + w) << 1));

    h16x16 o;
    // voxel v0 (w):    x=c0, y=c1
    o[0]  = (_Float16)A.x; o[1]  = (_Float16)A.y;    // d0h0
    o[2]  = (_Float16)B.x; o[3]  = (_Float16)B.y;    // d0h1
    o[4]  = (_Float16)C.x; o[5]  = (_Float16)C.y;    // d1h0
    o[6]  = (_Float16)D.x; o[7]  = (_Float16)D.y;    // d1h1
    // voxel v0+1 (w+1): z=c0, w=c1
    o[8]  = (_Float16)A.z; o[9]  = (_Float16)A.w;
    o[10] = (_Float16)B.z; o[11] = (_Float16)B.w;
    o[12] = (_Float16)C.z; o[13] = (_Float16)C.w;
    o[14] = (_Float16)D.z; o[15] = (_Float16)D.w;
    *(h16x16*)(pk + ((long long)v0 << 3)) = o;       // 32B at byte 16*v0
}

// ================= R11 main: forced-MLP, one batch per dispatch ============
__global__ __launch_bounds__(BLK, 4) void st_warp_kernel_pk16(
    const _Float16* __restrict__ pk,
    const float* __restrict__ trf,
    float* __restrict__ out,
    const int b)
{
    const int tid = threadIdx.x;
    const int sl  = blockIdx.x & 7;          // h-slice region (XCD heuristic)
    const int j   = blockIdx.x >> 3;         // 0..499 within region
    const int h0  = sl * HQ2;                // h-slice origin

    // ---- phase 0: indices (computed once) + ALL trf loads ----
    int   gvox[V], dk[V], hk[V], wk[V];
    float sd[V], sh[V], sw[V];
    #pragma unroll
    for (int k = 0; k < V; ++k) {
        const int v   = j * (BLK * V) + k * BLK + tid;   // region-linear voxel
        const int d   = v / RSTRIP2;
        const int rem = v - d * RSTRIP2;
        const int hh  = rem / Wn;
        const int w   = rem - hh * Wn;
        dk[k] = d; hk[k] = h0 + hh; wk[k] = w;
        gvox[k] = ((b * Dn + d) * Hn + (h0 + hh)) * Wn + w;
    }
    #pragma unroll
    for (int k = 0; k < V; ++k) {
        const float* tp = trf + (long long)gvox[k] * 3;
        sd[k] = __builtin_nontemporal_load(tp + 0);
        sh[k] = __builtin_nontemporal_load(tp + 1);
        sw[k] = __builtin_nontemporal_load(tp + 2);
    }
    __builtin_amdgcn_sched_barrier(0);   // keep all 12 trf loads issued here

    // ---- phase 1: weights + issue ALL V cell gathers (2 dwordx4 each) ----
    h16x16 val[V];
    float wA[V], wB[V], wC[V], wD[V], w0[V], w1[V];
    #pragma unroll
    for (int k = 0; k < V; ++k) {
        float loc, c0f, c1f;

        loc = (float)dk[k] + sd[k];
        c0f = fminf(fmaxf(floorf(loc), 0.0f), (float)(Dn - 1));
        c1f = fminf(c0f + 1.0f, (float)(Dn - 1));
        const float wd0 = c1f - loc, wd1 = 1.0f - wd0;
        const int id0 = (int)c0f;                 // id1 baked into packed data

        loc = (float)hk[k] + sh[k];
        c0f = fminf(fmaxf(floorf(loc), 0.0f), (float)(Hn - 1));
        c1f = fminf(c0f + 1.0f, (float)(Hn - 1));
        const float wh0 = c1f - loc, wh1 = 1.0f - wh0;
        const int ih0 = (int)c0f;                 // ih1 baked into packed data

        loc = (float)wk[k] + sw[k];
        c0f = fminf(fmaxf(floorf(loc), 0.0f), (float)(Wn - 1));
        c1f = fminf(c0f + 1.0f, (float)(Wn - 1));
        const float ww0 = c1f - loc, ww1 = 1.0f - ww0;
        const int iw0 = (int)c0f;

        const bool lo = (iw0 < Wn - 1);
        const int  m  = lo ? iw0 : (Wn - 2);
        // boundary: corner0 weight -> 0, corner1 weight -> 1 (exact: ww0+ww1==1)
        w0[k] = lo ? ww0 : 0.0f;
        w1[k] = lo ? ww1 : 1.0f;
        wA[k] = wd0 * wh0; wB[k] = wd0 * wh1;
        wC[k] = wd1 * wh0; wD[k] = wd1 * wh1;

        const long long p0 = ((b * Dn + id0) * Hn + ih0) * Wn + m;  // w-pair base
        val[k] = *(const h16x16*)(pk + (p0 << 3));   // 32B: cells p0, p0+1
    }
    __builtin_amdgcn_sched_barrier(0);   // keep all 8 cell loads issued here

    // ---- phase 2: convert + combine + store ----
    #pragma unroll
    for (int k = 0; k < V; ++k) {
        const h16x16 v = val[k];
        // layout: [i] w-corner0, [8+i] w-corner1; i = d*4 + h*2 + c
        const float acc0 =
              wA[k] * (w0[k] * (float)v[0] + w1[k] * (float)v[8])
            + wB[k] * (w0[k] * (float)v[2] + w1[k] * (float)v[10])
            + wC[k] * (w0[k] * (float)v[4] + w1[k] * (float)v[12])
            + wD[k] * (w0[k] * (float)v[6] + w1[k] * (float)v[14]);
        const float acc1 =
              wA[k] * (w0[k] * (float)v[1] + w1[k] * (float)v[9])
            + wB[k] * (w0[k] * (float)v[3] + w1[k] * (float)v[11])
            + wC[k] * (w0[k] * (float)v[5] + w1[k] * (float)v[13])
            + wD[k] * (w0[k] * (float)v[7] + w1[k] * (float)v[15]);
        f32x2 res; res.x = acc0; res.y = acc1;
        __builtin_nontemporal_store(res, &((f32x2*)out)[gvox[k]]);
    }
}

// ================= R8 tier: h-pair pack (known-good middle fallback) =======
__global__ __launch_bounds__(BLK) void repack_h_pairs(
    const float* __restrict__ vol, _Float16* __restrict__ pk)
{
    const int t  = blockIdx.x * BLK + threadIdx.x;   // 0 .. 4,095,999
    const int v0 = t * 2;                            // even voxel id
    const int w  = v0 % Wn;                          // even (Wn%2==0)
    const int r  = v0 / Wn;                          // row id = (b*Dn+d)*Hn+h
    const int h  = r % Hn;
    const int hc = (h < Hn - 1) ? (h + 1) : h;       // clamped h+1
    const int r1 = r - h + hc;                       // row id at hc

    const f32x4 a = *(const f32x4*)(vol + ((long long)v0 << 1));
    const f32x4 b = *(const f32x4*)(vol + ((long long)(r1 * Wn + w) << 1));

    h16x8 o;
    o[0] = (_Float16)a.x; o[1] = (_Float16)a.y;
    o[2] = (_Float16)b.x; o[3] = (_Float16)b.y;
    o[4] = (_Float16)a.z; o[5] = (_Float16)a.w;
    o[6] = (_Float16)b.z; o[7] = (_Float16)b.w;
    *(h16x8*)(pk + ((long long)v0 << 2)) = o;
}

__global__ __launch_bounds__(BLK, 4) void st_warp_kernel_pk(
    const _Float16* __restrict__ pk,
    const float* __restrict__ trf,
    float* __restrict__ out)
{
    const int tid = threadIdx.x;
    const int xcd = blockIdx.x & 7;
    const int j   = blockIdx.x >> 3;
    const int b   = xcd >> 2;
    const int h0  = (xcd & 3) * HQ;

    int   gvox[V];
    float sd[V], sh[V], sw[V];
    #pragma unroll
    for (int k = 0; k < V; ++k) {
        const int v   = j * (BLK * V) + k * BLK + tid;
        const int d   = v / RSTRIP;
        const int rem = v - d * RSTRIP;
        const int hh  = rem / Wn;
        const int w   = rem - hh * Wn;
        gvox[k] = ((b * Dn + d) * Hn + (h0 + hh)) * Wn + w;
    }
    #pragma unroll
    for (int k = 0; k < V; ++k) {
        const float* tp = trf + (long long)gvox[k] * 3;
        sd[k] = __builtin_nontemporal_load(tp + 0);
        sh[k] = __builtin_nontemporal_load(tp + 1);
        sw[k] = __builtin_nontemporal_load(tp + 2);
    }

    h16x8 val[2 * V];
    float wA[V], wB[V], wC[V], wD[V], w0[V], w1[V];
    #pragma unroll
    for (int k = 0; k < V; ++k) {
        const int v   = j * (BLK * V) + k * BLK + tid;
        const int d   = v / RSTRIP;
        const int rem = v - d * RSTRIP;
        const int hh  = rem / Wn;
        const int w   = rem - hh * Wn;
        const int h   = h0 + hh;

        float loc, c0f, c1f;

        loc = (float)d + sd[k];
        c0f = fminf(fmaxf(floorf(loc), 0.0f), (float)(Dn - 1));
        c1f = fminf(c0f + 1.0f, (float)(Dn - 1));
        const float wd0 = c1f - loc, wd1 = 1.0f - wd0;
        const int id0 = (int)c0f, id1 = (int)c1f;

        loc = (float)h + sh[k];
        c0f = fminf(fmaxf(floorf(loc), 0.0f), (float)(Hn - 1));
        c1f = fminf(c0f + 1.0f, (float)(Hn - 1));
        const float wh0 = c1f - loc, wh1 = 1.0f - wh0;
        const int ih0 = (int)c0f;

        loc = (float)w + sw[k];
        c0f = fminf(fmaxf(floorf(loc), 0.0f), (float)(Wn - 1));
        c1f = fminf(c0f + 1.0f, (float)(Wn - 1));
        const float ww0 = c1f - loc, ww1 = 1.0f - ww0;
        const int iw0 = (int)c0f;

        const bool lo = (iw0 < Wn - 1);
        const int  m  = lo ? iw0 : (Wn - 2);
        w0[k] = lo ? ww0 : 0.0f;
        w1[k] = lo ? ww1 : 1.0f;
        wA[k] = wd0 * wh0; wB[k] = wd0 * wh1;
        wC[k] = wd1 * wh0; wD[k] = wd1 * wh1;

        const int bo = b * Dn;
        const int p0 = ((bo + id0) * Hn + ih0) * Wn + m;
        const int p1 = ((bo + id1) * Hn + ih0) * Wn + m;

        val[2 * k + 0] = *(const h16x8*)(pk + ((long long)p0 << 2));
        val[2 * k + 1] = *(const h16x8*)(pk + ((long long)p1 << 2));
    }

    #pragma unroll
    for (int k = 0; k < V; ++k) {
        const h16x8 a = val[2 * k + 0];
        const h16x8 c = val[2 * k + 1];
        const float acc0 =
              wA[k] * (w0[k] * (float)a[0] + w1[k] * (float)a[4])
            + wB[k] * (w0[k] * (float)a[2] + w1[k] * (float)a[6])
            + wC[k] * (w0[k] * (float)c[0] + w1[k] * (float)c[4])
            + wD[k] * (w0[k] * (float)c[2] + w1[k] * (float)c[6]);
        const float acc1 =
              wA[k] * (w0[k] * (float)a[1] + w1[k] * (float)a[5])
            + wB[k] * (w0[k] * (float)a[3] + w1[k] * (float)a[7])
            + wC[k] * (w0[k] * (float)c[1] + w1[k] * (float)c[5])
            + wD[k] * (w0[k] * (float)c[3] + w1[k] * (float)c[7]);
        f32x2 res; res.x = acc0; res.y = acc1;
        __builtin_nontemporal_store(res, &((f32x2*)out)[gvox[k]]);
    }
}

// ================= R5 tier: f32 direct (last-resort fallback) ==============
__global__ __launch_bounds__(BLK, 4) void st_warp_kernel_f32(
    const float* __restrict__ vol,
    const float* __restrict__ trf,
    float* __restrict__ out)
{
    const int tid = threadIdx.x;
    const int xcd = blockIdx.x & 7;
    const int j   = blockIdx.x >> 3;
    const int b   = xcd >> 2;
    const int h0  = (xcd & 3) * HQ;

    int   gvox[V];
    float sd[V], sh[V], sw[V];
    #pragma unroll
    for (int k = 0; k < V; ++k) {
        const int v   = j * (BLK * V) + k * BLK + tid;
        const int d   = v / RSTRIP;
        const int rem = v - d * RSTRIP;
        const int hh  = rem / Wn;
        const int w   = rem - hh * Wn;
        gvox[k] = ((b * Dn + d) * Hn + (h0 + hh)) * Wn + w;
    }
    #pragma unroll
    for (int k = 0; k < V; ++k) {
        const float* tp = trf + (long long)gvox[k] * 3;
        sd[k] = __builtin_nontemporal_load(tp + 0);
        sh[k] = __builtin_nontemporal_load(tp + 1);
        sw[k] = __builtin_nontemporal_load(tp + 2);
    }

    f32x4 val[4 * V];
    float wA[V], wB[V], wC[V], wD[V], w0[V], w1[V];
    #pragma unroll
    for (int k = 0; k < V; ++k) {
        const int v   = j * (BLK * V) + k * BLK + tid;
        const int d   = v / RSTRIP;
        const int rem = v - d * RSTRIP;
        const int hh  = rem / Wn;
        const int w   = rem - hh * Wn;
        const int h   = h0 + hh;

        float loc, c0f, c1f;

        loc = (float)d + sd[k];
        c0f = fminf(fmaxf(floorf(loc), 0.0f), (float)(Dn - 1));
        c1f = fminf(c0f + 1.0f, (float)(Dn - 1));
        const float wd0 = c1f - loc, wd1 = 1.0f - wd0;
        const int id0 = (int)c0f, id1 = (int)c1f;

        loc = (float)h + sh[k];
        c0f = fminf(fmaxf(floorf(loc), 0.0f), (float)(Hn - 1));
        c1f = fminf(c0f + 1.0f, (float)(Hn - 1));
        const float wh0 = c1f - loc, wh1 = 1.0f - wh0;
        const int ih0 = (int)c0f, ih1 = (int)c1f;

        loc = (float)w + sw[k];
        c0f = fminf(fmaxf(floorf(loc), 0.0f), (float)(Wn - 1));
        c1f = fminf(c0f + 1.0f, (float)(Wn - 1));
        const float ww0 = c1f - loc, ww1 = 1.0f - ww0;
        const int iw0 = (int)c0f;

        const bool lo = (iw0 < Wn - 1);
        const int  m  = lo ? iw0 : (Wn - 2);
        w0[k] = lo ? ww0 : 0.0f;
        w1[k] = lo ? ww1 : 1.0f;
        wA[k] = wd0 * wh0; wB[k] = wd0 * wh1;
        wC[k] = wd1 * wh0; wD[k] = wd1 * wh1;

        const int bo  = b * Dn;
        const int r00 = ((bo + id0) * Hn + ih0) * Wn;
        const int r01 = ((bo + id0) * Hn + ih1) * Wn;
        const int r10 = ((bo + id1) * Hn + ih0) * Wn;
        const int r11 = ((bo + id1) * Hn + ih1) * Wn;

        val[4 * k + 0] = *(const f32x4*)(vol + (((long long)(r00 + m)) << 1));
        val[4 * k + 1] = *(const f32x4*)(vol + (((long long)(r01 + m)) << 1));
        val[4 * k + 2] = *(const f32x4*)(vol + (((long long)(r10 + m)) << 1));
        val[4 * k + 3] = *(const f32x4*)(vol + (((long long)(r11 + m)) << 1));
    }

    #pragma unroll
    for (int k = 0; k < V; ++k) {
        const f32x4 vA = val[4 * k + 0], vB = val[4 * k + 1];
        const f32x4 vC = val[4 * k + 2], vD = val[4 * k + 3];
        const float acc0 = wA[k] * (w0[k] * vA.x + w1[k] * vA.z)
                         + wB[k] * (w0[k] * vB.x + w1[k] * vB.z)
                         + wC[k] * (w0[k] * vC.x + w1[k] * vC.z)
                         + wD[k] * (w0[k] * vD.x + w1[k] * vD.z);
        const float acc1 = wA[k] * (w0[k] * vA.y + w1[k] * vA.w)
                         + wB[k] * (w0[k] * vB.y + w1[k] * vB.w)
                         + wC[k] * (w0[k] * vC.y + w1[k] * vC.w)
                         + wD[k] * (w0[k] * vD.y + w1[k] * vD.w);
        f32x2 res; res.x = acc0; res.y = acc1;
        __builtin_nontemporal_store(res, &((f32x2*)out)[gvox[k]]);
    }
}

extern "C" void kernel_launch(void* const* d_in, const int* in_sizes, int n_in,
                              void* d_out, int out_size, void* d_ws, size_t ws_size,
                              hipStream_t stream) {
    const float* vol = (const float*)d_in[0];
    const float* trf = (const float*)d_in[1];
    float* out = (float*)d_out;

    const int nvox = Bn * Dn * Hn * Wn;               // 8,192,000
    const size_t pk16_bytes = (size_t)nvox * 8 * sizeof(_Float16);  // 131,072,000
    const size_t pk8_bytes  = (size_t)nvox * 4 * sizeof(_Float16);  //  65,536,000
    const int rgrid = (nvox / 2) / BLK;               // 16000 blocks

    if (d_ws != nullptr && ws_size >= pk16_bytes) {
        _Float16* pk = (_Float16*)d_ws;
        const int hgrid = (nvox / 2) / (BLK * V);     // 4000 blocks per batch, %8==0
        repack_dh<<<rgrid, BLK, 0, stream>>>(vol, pk);
        st_warp_kernel_pk16<<<hgrid, BLK, 0, stream>>>(pk, trf, out, 0);
        st_warp_kernel_pk16<<<hgrid, BLK, 0, stream>>>(pk, trf, out, 1);
    } else if (d_ws != nullptr && ws_size >= pk8_bytes) {
        _Float16* pk = (_Float16*)d_ws;
        const int grid = nvox / (BLK * V);            // 8000 blocks
        repack_h_pairs<<<rgrid, BLK, 0, stream>>>(vol, pk);
        st_warp_kernel_pk<<<grid, BLK, 0, stream>>>(pk, trf, out);
    } else {
        const int grid = nvox / (BLK * V);
        st_warp_kernel_f32<<<grid, BLK, 0, stream>>>(vol, trf, out);
    }
}